// Round 6
// baseline (256.652 us; speedup 1.0000x reference)
//
#include <hip/hip_runtime.h>

#define N 4096
#define CORE_W 116        // core columns per strip
#define NSTRIP 36         // 36*116 = 4176 >= 4096
#define ROWS 74           // output rows per wave; steps = ROWS+13 = 87
#define NCHUNK 56         // 56*74 = 4144 >= 4096
#define NSLOT 32          // atomic spreading slots (32 copies of 2 counters)
// grid = 36 x 56 = 2016 single-wave blocks = one residency round at
// 2 waves/SIMD (8 blocks/CU x 252 CUs), wg-slot limit 16/CU not binding.

// R6: SKEWED PIPELINE. R2-R5 pinned the bottleneck: per-wave per-step wall
// ~5400 cyc (VALU issue only ~590) -- the serial 6-unit chain
// feed->s1->..->s5 (each unit: 2 ds_bpermute shuffles ~120cy + exp2/rcp)
// stalls each wave ~4800 cyc/step, and TLP is VGPR-capped at 4 waves/SIMD
// (forcing lower spills: R1, R3). Fix: skew stages so one step's stages
// are independent: feed does row t+1; s1(row t-1)+s2(t-2) paired;
// s3(t-4)+s4(t-5) consume s1/s2 outputs from PREVIOUS steps; s5(t-7).
// 4 independent chains/step, max chain 2 units. Registers +~20 for deeper
// rings -> run 2 waves/SIMD deliberately (launch_bounds(64,2), cap 128,
// NO forced squeeze): issue demand 2x550 > chain ~600 -> issue-bound.
// Warm-up cascade (re-derived): h0 exact rows>=t0; iter1>=t0+2;
// iter2>=t0+3; iter3>=t0+4; iter4>=t0+5; iter5>=t0+6 -> t0 = R0-6.
// Drain: last output row R1-1 at step R1+6 -> jmax = (R1-R0)+13.
// gt is read via TWO rings: gA (load row t+1; s1,s2) and gB (load row
// t-3, an L2-hot re-read; s3,s4,s5) -- keeps ring sizes in {2,3,4,6} so a
// 12x-unrolled body has compile-time slot indices ((jb%12)==0).
// Tripwire: WRITE_SIZE ~0.3MB (no spill). Occupancy ~25% is INTENTIONAL.

typedef float2 f2;
__device__ __forceinline__ f2 mkf2(float a, float b){ f2 r; r.x=a; r.y=b; return r; }

__device__ __forceinline__ f2 hsum(f2 v) {
    float m = v.x + v.y;
    float L = __shfl_up(v.y, 1);     // lane l-1's right col (intra-wave, width 64)
    float R = __shfl_down(v.x, 1);   // lane l+1's left col
    return mkf2(L + m, m + R);
}

__device__ __forceinline__ f2 stepf(f2 p, f2 d, f2 g, f2* fn) {
    const float C1 = 28.853900817779268f;   // 20*log2(e)
    const float C2 = 14.426950408889634f;   // 10*log2(e)
    f2 o, f;
    {
        float dd = fminf(fmaxf(d.x, 0.f), 1.f);      // v_med3_f32
        float u  = __builtin_fmaf(p.x - dd, C1, C2);
        float sh = __builtin_amdgcn_rcpf(1.f + __builtin_amdgcn_exp2f(u));
        f.x = g.x * sh; o.x = p.x + f.x;
    }
    {
        float dd = fminf(fmaxf(d.y, 0.f), 1.f);
        float u  = __builtin_fmaf(p.y - dd, C1, C2);
        float sh = __builtin_amdgcn_rcpf(1.f + __builtin_amdgcn_exp2f(u));
        f.y = g.y * sh; o.y = p.y + f.y;
    }
    *fn = f;
    return o;
}

__device__ __forceinline__ f2 ldrow(const float* __restrict__ base, int row,
                                    int gc, bool edge) {
    if (row < 0 || row >= N) return mkf2(0.f, 0.f);
    if (!edge) return *(const f2*)(base + (size_t)row * N + gc);  // gc even -> aligned
    float a = 0.f, b = 0.f;
    if (gc >= 0 && gc < N)         a = base[(size_t)row * N + gc];
    if (gc + 1 >= 0 && gc + 1 < N) b = base[(size_t)row * N + gc + 1];
    return mkf2(a, b);
}

__global__ __launch_bounds__(64, 2) void wlc_main(
    const float* __restrict__ pred,
    const float* __restrict__ gt,
    float* __restrict__ ws)
{
    const int lane  = threadIdx.x;       // single-wave block
    const int strip = blockIdx.x;
    const int chunk = blockIdx.y;
    const int x0 = strip * CORE_W - 6;
    const int gc = x0 + 2 * lane;
    const bool edge = (strip == 0) || (strip == NSTRIP - 1);

    const int R0 = chunk * ROWS;
    const int R1 = min(R0 + ROWS, N);
    const int t0 = R0 - 6;               // 6-row warm-up (skewed cascade)
    const int jmax = (R1 - R0) + 13;     // last step t = R1+6 (s5 row R1-1)

    // column masks, applied once in epilogue
    const float colm = (lane >= 3 && lane <= 60) ? 1.f : 0.f;
    const float m0 = (gc     < N) ? colm : 0.f;
    const float m1 = (gc + 1 < N) ? colm : 0.f;

    // rings, slot = (row - t0) mod size; all zero-init (finite garbage,
    // annihilated by w=0 selects)
    f2 pr[4], gA[4], gB[6];              // pred; gt-early (s1,s2); gt-late (s3..s5)
    f2 h0r[3], h2r[3], h4r[3];           // hsum rings (sum-all snapshots)
    f2 hp1, ps1, hp3, ps3;               // running pair-sums for unskewed s2, s4
    f2 o1r[2], o2r[3], o3r[2], o4r[3];   // iter outputs
#pragma unroll
    for (int i = 0; i < 4; ++i) { pr[i] = mkf2(0,0); gA[i] = mkf2(0,0); }
#pragma unroll
    for (int i = 0; i < 6; ++i) gB[i] = mkf2(0,0);
#pragma unroll
    for (int i = 0; i < 3; ++i) { h0r[i]=h2r[i]=h4r[i]=mkf2(0,0);
                                  o2r[i]=o4r[i]=mkf2(0,0); }
    hp1=ps1=hp3=ps3=mkf2(0,0);
    o1r[0]=o1r[1]=o3r[0]=o3r[1]=mkf2(0,0);

    // prologue: pred rows t0 (slot 0), t0+1 (slot 1)
    pr[0] = ldrow(pred, t0,     gc, edge);
    pr[1] = ldrow(pred, t0 + 1, gc, edge);

    f2 swv = mkf2(0.f, 0.f);             // weighted fn total (unmasked)
    f2 gsv = mkf2(0.f, 0.f);             // gt total (unmasked)

    // compile-time slot macros: (j + c) % m == (k + c) % m since 12 | jb
#define M4(c) ((k + 16 + (c)) & 3)
#define M3(c) ((k + 18 + (c)) % 3)
#define M2(c) ((k + 16 + (c)) & 1)
#define M6(c) ((k + 18 + (c)) % 6)

    for (int jb = 0; jb < jmax; jb += 12) {
#pragma unroll
        for (int k = 0; k < 12; ++k) {
            const int j = jb + k;
            const int t = t0 + j;
            if (j < jmax) {
                // prefetches (rows OOB -> ldrow zeros; guards trim drain loads)
                if (t + 2 <= R1 + 4) pr[M4(2)] = ldrow(pred, t + 2, gc, edge);
                if (t + 1 <= R1 + 3) gA[M4(1)] = ldrow(gt,   t + 1, gc, edge);
                if (t     <= R1 + 4) gB[M6(3)] = ldrow(gt,   t - 3, gc, edge);

                // uniform guarded weights (SGPR selects, branch-free)
                const float w1 = (t-1 >= R0 && t-1 < R1) ? 1.f  : 0.f;
                const float w2 = (t-2 >= R0 && t-2 < R1) ? 4.f  : 0.f;
                const float w3 = (t-4 >= R0 && t-4 < R1) ? 9.f  : 0.f;
                const float w4 = (t-5 >= R0 && t-5 < R1) ? 16.f : 0.f;
                const bool  in5 = (t-7 >= R0 && t-7 < R1);
                const float w5 = in5 ? 25.f : 0.f;
                const float g1 = in5 ? 1.f  : 0.f;

                // ring snapshots BEFORE this step's pushes:
                // d1 = h0 rows t-2..t; d3 = h2 rows t-5..t-3; d5 = h4 rows t-8..t-6
                const f2 d1 = mkf2(h0r[0].x+h0r[1].x+h0r[2].x, h0r[0].y+h0r[1].y+h0r[2].y);
                const f2 d3 = mkf2(h2r[0].x+h2r[1].x+h2r[2].x, h2r[0].y+h2r[1].y+h2r[2].y);
                const f2 d5 = mkf2(h4r[0].x+h4r[1].x+h4r[2].x, h4r[0].y+h4r[1].y+h4r[2].y);

                f2 fn, o, hn;

                // feed (independent): h0 of pred row t+1
                h0r[M3(1)] = hsum(pr[M4(1)]);

                // chain A: stage1 (row t-1) -> stage2 (row t-2)
                o = stepf(pr[M4(3)], d1, gA[M4(3)], &fn);
                swv.x = __builtin_fmaf(w1, fn.x, swv.x);
                swv.y = __builtin_fmaf(w1, fn.y, swv.y);
                hn = hsum(o);
                const f2 d2 = mkf2(hn.x + ps1.x, hn.y + ps1.y);   // h1 rows t-3..t-1
                ps1 = mkf2(hn.x + hp1.x, hn.y + hp1.y);
                hp1 = hn;
                o1r[M2(1)] = o;

                o = stepf(o1r[M2(0)], d2, gA[M4(2)], &fn);
                swv.x = __builtin_fmaf(w2, fn.x, swv.x);
                swv.y = __builtin_fmaf(w2, fn.y, swv.y);
                h2r[M3(1)] = hsum(o);          // after d3 snapshot
                o2r[M3(1)] = o;

                // chain B: stage3 (row t-4) -> stage4 (row t-5)
                o = stepf(o2r[M3(2)], d3, gB[M6(2)], &fn);
                swv.x = __builtin_fmaf(w3, fn.x, swv.x);
                swv.y = __builtin_fmaf(w3, fn.y, swv.y);
                hn = hsum(o);
                const f2 d4 = mkf2(hn.x + ps3.x, hn.y + ps3.y);   // h3 rows t-6..t-4
                ps3 = mkf2(hn.x + hp3.x, hn.y + hp3.y);
                hp3 = hn;
                o3r[M2(0)] = o;

                o = stepf(o3r[M2(1)], d4, gB[M6(1)], &fn);
                swv.x = __builtin_fmaf(w4, fn.x, swv.x);
                swv.y = __builtin_fmaf(w4, fn.y, swv.y);
                h4r[M3(1)] = hsum(o);          // after d5 snapshot
                o4r[M3(1)] = o;

                // chain C: stage5 (row t-7), output not fed forward
                {
                    const f2 g5 = gB[M6(5)];
                    o = stepf(o4r[M3(2)], d5, g5, &fn);
                    swv.x = __builtin_fmaf(w5, fn.x, swv.x);
                    swv.y = __builtin_fmaf(w5, fn.y, swv.y);
                    gsv.x = __builtin_fmaf(g1, g5.x, gsv.x);
                    gsv.y = __builtin_fmaf(g1, g5.y, gsv.y);
                }
            }
        }
    }
#undef M4
#undef M3
#undef M2
#undef M6

    // apply step-invariant column masks ONCE, wave-reduce, 2 atomics
    float vals[2];
    vals[0] = gsv.x * m0 + gsv.y * m1;
    vals[1] = swv.x * m0 + swv.y * m1;
    const int slot = (strip + chunk * NSTRIP) & (NSLOT - 1);
#pragma unroll
    for (int kk = 0; kk < 2; ++kk) {
        float v = vals[kk];
#pragma unroll
        for (int off = 32; off > 0; off >>= 1)
            v += __shfl_down(v, off, 64);
        if (lane == 0) atomicAdd(&ws[slot * 32 + kk], v);
    }
}

__global__ __launch_bounds__(64) void wlc_final(const float* __restrict__ ws,
                                                float* __restrict__ out)
{
    const int lane = threadIdx.x;
    float t0 = (lane < NSLOT) ? ws[lane * 32 + 0] : 0.f;
    float t1 = (lane < NSLOT) ? ws[lane * 32 + 1] : 0.f;
#pragma unroll
    for (int off = 32; off > 0; off >>= 1) {
        t0 += __shfl_down(t0, off, 64);
        t1 += __shfl_down(t1, off, 64);
    }
    if (lane == 0)
        out[0] = t1 / t0;
}

extern "C" void kernel_launch(void* const* d_in, const int* in_sizes, int n_in,
                              void* d_out, int out_size, void* d_ws, size_t ws_size,
                              hipStream_t stream)
{
    const float* pred = (const float*)d_in[0];
    const float* gtp  = (const float*)d_in[1];
    float* ws = (float*)d_ws;

    hipMemsetAsync(d_ws, 0, NSLOT * 32 * sizeof(float), stream);

    wlc_main<<<dim3(NSTRIP, NCHUNK), 64, 0, stream>>>(pred, gtp, ws);
    wlc_final<<<1, 64, 0, stream>>>(ws, (float*)d_out);
}

// Round 7
// 206.150 us; speedup vs baseline: 1.2450x; 1.2450x over previous
//
#include <hip/hip_runtime.h>

#define N 4096
#define CORE_W 116        // core columns per strip
#define NSTRIP 36         // 36*116 = 4176 >= 4096
#define ROWS 37           // output rows per wave; steps = ROWS+13 = 50
#define NCHUNK 112        // 112*37 = 4144 >= 4096 (chunk 111 is empty-safe)
#define NSLOT 32          // atomic spreading slots (32 copies of 2 counters)
#define WPB 4             // waves per block (independent waves, no barriers)
#define NBLOCK ((NSTRIP * NCHUNK) / WPB)   // 4032/4 = 1008 <= 1024 resident

// R7 = R6 skewed datapath x R4 concurrency.
// Per-wave step wall (dur x concurrency / wave-steps): R0 3934, R4 3343,
// R5 3580, R6-skew 2530 cyc -- the stage-skew DID cut the critical path
// 24%; R6 lost only because 1-wave blocks + 2016-wave grid collapsed
// concurrency to ~1170 waves (occ 14%). Fix: WPB=4 packed 256-thread
// blocks (no wg-slot limit) and 4032 waves = 1008 blocks <= 1024 capacity
// at 4 waves/SIMD (VGPR=60 measured for this body). launch_bounds(256,4)
// caps 64 VGPR: 4-reg slack vs measured 60 (unlike R3's -12 squeeze).
// Tripwires: VGPR<=64, WRITE_SIZE ~0.3MB (no spill).
//
// Skew structure (R6, verified absmax=0): feed does h0(row t+1);
// s1(t-1)->s2(t-2) paired; s3(t-4)->s4(t-5) consume earlier steps'
// outputs; s5(t-7). 4 independent chains/step, max chain 2 stepf units.
// Warm-up cascade: t0 = R0-6; drain jmax = (R1-R0)+13. gt via two rings:
// gA (row t+1; s1,s2), gB (row t-3, L2-hot re-read; s3..s5). Ring sizes
// {4,3,2,6} -> 12x unrolled body keeps slot indices compile-time.

typedef float2 f2;
__device__ __forceinline__ f2 mkf2(float a, float b){ f2 r; r.x=a; r.y=b; return r; }

__device__ __forceinline__ f2 hsum(f2 v) {
    float m = v.x + v.y;
    float L = __shfl_up(v.y, 1);     // lane l-1's right col (intra-wave, width 64)
    float R = __shfl_down(v.x, 1);   // lane l+1's left col
    return mkf2(L + m, m + R);
}

__device__ __forceinline__ f2 stepf(f2 p, f2 d, f2 g, f2* fn) {
    const float C1 = 28.853900817779268f;   // 20*log2(e)
    const float C2 = 14.426950408889634f;   // 10*log2(e)
    f2 o, f;
    {
        float dd = fminf(fmaxf(d.x, 0.f), 1.f);      // v_med3_f32
        float u  = __builtin_fmaf(p.x - dd, C1, C2);
        float sh = __builtin_amdgcn_rcpf(1.f + __builtin_amdgcn_exp2f(u));
        f.x = g.x * sh; o.x = p.x + f.x;
    }
    {
        float dd = fminf(fmaxf(d.y, 0.f), 1.f);
        float u  = __builtin_fmaf(p.y - dd, C1, C2);
        float sh = __builtin_amdgcn_rcpf(1.f + __builtin_amdgcn_exp2f(u));
        f.y = g.y * sh; o.y = p.y + f.y;
    }
    *fn = f;
    return o;
}

__device__ __forceinline__ f2 ldrow(const float* __restrict__ base, int row,
                                    int gc, bool edge) {
    if (row < 0 || row >= N) return mkf2(0.f, 0.f);
    if (!edge) return *(const f2*)(base + (size_t)row * N + gc);  // gc even -> aligned
    float a = 0.f, b = 0.f;
    if (gc >= 0 && gc < N)         a = base[(size_t)row * N + gc];
    if (gc + 1 >= 0 && gc + 1 < N) b = base[(size_t)row * N + gc + 1];
    return mkf2(a, b);
}

__global__ __launch_bounds__(64 * WPB, 4) void wlc_main(
    const float* __restrict__ pred,
    const float* __restrict__ gt,
    float* __restrict__ ws)
{
    const int lane   = threadIdx.x & 63;
    const int wid    = threadIdx.x >> 6;
    const int linear = blockIdx.x * WPB + wid;      // adjacent strips share a block
    const int strip  = linear % NSTRIP;
    const int chunk  = linear / NSTRIP;
    const int x0 = strip * CORE_W - 6;
    const int gc = x0 + 2 * lane;
    const bool edge = (strip == 0) || (strip == NSTRIP - 1);

    const int R0 = chunk * ROWS;
    const int R1 = min(R0 + ROWS, N);
    const int t0 = R0 - 6;               // 6-row warm-up (skewed cascade)
    const int jmax = (R1 - R0) + 13;     // last step t = R1+6 (s5 row R1-1)

    // column masks, applied once in epilogue
    const float colm = (lane >= 3 && lane <= 60) ? 1.f : 0.f;
    const float m0 = (gc     < N) ? colm : 0.f;
    const float m1 = (gc + 1 < N) ? colm : 0.f;

    // rings, slot = (row - t0) mod size; all zero-init (finite garbage,
    // annihilated by w=0 selects)
    f2 pr[4], gA[4], gB[6];              // pred; gt-early (s1,s2); gt-late (s3..s5)
    f2 h0r[3], h2r[3], h4r[3];           // hsum rings (sum-all snapshots)
    f2 hp1, ps1, hp3, ps3;               // running pair-sums for unskewed s2, s4
    f2 o1r[2], o2r[3], o3r[2], o4r[3];   // iter outputs
#pragma unroll
    for (int i = 0; i < 4; ++i) { pr[i] = mkf2(0,0); gA[i] = mkf2(0,0); }
#pragma unroll
    for (int i = 0; i < 6; ++i) gB[i] = mkf2(0,0);
#pragma unroll
    for (int i = 0; i < 3; ++i) { h0r[i]=h2r[i]=h4r[i]=mkf2(0,0);
                                  o2r[i]=o4r[i]=mkf2(0,0); }
    hp1=ps1=hp3=ps3=mkf2(0,0);
    o1r[0]=o1r[1]=o3r[0]=o3r[1]=mkf2(0,0);

    // prologue: pred rows t0 (slot 0), t0+1 (slot 1)
    pr[0] = ldrow(pred, t0,     gc, edge);
    pr[1] = ldrow(pred, t0 + 1, gc, edge);

    f2 swv = mkf2(0.f, 0.f);             // weighted fn total (unmasked)
    f2 gsv = mkf2(0.f, 0.f);             // gt total (unmasked)

    // compile-time slot macros: (j + c) % m == (k + c) % m since 12 | jb
#define M4(c) ((k + 16 + (c)) & 3)
#define M3(c) ((k + 18 + (c)) % 3)
#define M2(c) ((k + 16 + (c)) & 1)
#define M6(c) ((k + 18 + (c)) % 6)

    for (int jb = 0; jb < jmax; jb += 12) {
#pragma unroll
        for (int k = 0; k < 12; ++k) {
            const int j = jb + k;
            const int t = t0 + j;
            if (j < jmax) {
                // prefetches (rows OOB -> ldrow zeros; guards trim drain loads)
                if (t + 2 <= R1 + 4) pr[M4(2)] = ldrow(pred, t + 2, gc, edge);
                if (t + 1 <= R1 + 3) gA[M4(1)] = ldrow(gt,   t + 1, gc, edge);
                if (t     <= R1 + 4) gB[M6(3)] = ldrow(gt,   t - 3, gc, edge);

                // uniform guarded weights (SGPR selects, branch-free)
                const float w1 = (t-1 >= R0 && t-1 < R1) ? 1.f  : 0.f;
                const float w2 = (t-2 >= R0 && t-2 < R1) ? 4.f  : 0.f;
                const float w3 = (t-4 >= R0 && t-4 < R1) ? 9.f  : 0.f;
                const float w4 = (t-5 >= R0 && t-5 < R1) ? 16.f : 0.f;
                const bool  in5 = (t-7 >= R0 && t-7 < R1);
                const float w5 = in5 ? 25.f : 0.f;
                const float g1 = in5 ? 1.f  : 0.f;

                // ring snapshots BEFORE this step's pushes:
                // d1 = h0 rows t-2..t; d3 = h2 rows t-5..t-3; d5 = h4 rows t-8..t-6
                const f2 d1 = mkf2(h0r[0].x+h0r[1].x+h0r[2].x, h0r[0].y+h0r[1].y+h0r[2].y);
                const f2 d3 = mkf2(h2r[0].x+h2r[1].x+h2r[2].x, h2r[0].y+h2r[1].y+h2r[2].y);
                const f2 d5 = mkf2(h4r[0].x+h4r[1].x+h4r[2].x, h4r[0].y+h4r[1].y+h4r[2].y);

                f2 fn, o, hn;

                // feed (independent): h0 of pred row t+1
                h0r[M3(1)] = hsum(pr[M4(1)]);

                // chain A: stage1 (row t-1) -> stage2 (row t-2)
                o = stepf(pr[M4(3)], d1, gA[M4(3)], &fn);
                swv.x = __builtin_fmaf(w1, fn.x, swv.x);
                swv.y = __builtin_fmaf(w1, fn.y, swv.y);
                hn = hsum(o);
                const f2 d2 = mkf2(hn.x + ps1.x, hn.y + ps1.y);   // h1 rows t-3..t-1
                ps1 = mkf2(hn.x + hp1.x, hn.y + hp1.y);
                hp1 = hn;
                o1r[M2(1)] = o;

                o = stepf(o1r[M2(0)], d2, gA[M4(2)], &fn);
                swv.x = __builtin_fmaf(w2, fn.x, swv.x);
                swv.y = __builtin_fmaf(w2, fn.y, swv.y);
                h2r[M3(1)] = hsum(o);          // after d3 snapshot
                o2r[M3(1)] = o;

                // chain B: stage3 (row t-4) -> stage4 (row t-5)
                o = stepf(o2r[M3(2)], d3, gB[M6(2)], &fn);
                swv.x = __builtin_fmaf(w3, fn.x, swv.x);
                swv.y = __builtin_fmaf(w3, fn.y, swv.y);
                hn = hsum(o);
                const f2 d4 = mkf2(hn.x + ps3.x, hn.y + ps3.y);   // h3 rows t-6..t-4
                ps3 = mkf2(hn.x + hp3.x, hn.y + hp3.y);
                hp3 = hn;
                o3r[M2(0)] = o;

                o = stepf(o3r[M2(1)], d4, gB[M6(1)], &fn);
                swv.x = __builtin_fmaf(w4, fn.x, swv.x);
                swv.y = __builtin_fmaf(w4, fn.y, swv.y);
                h4r[M3(1)] = hsum(o);          // after d5 snapshot
                o4r[M3(1)] = o;

                // chain C: stage5 (row t-7), output not fed forward
                {
                    const f2 g5 = gB[M6(5)];
                    o = stepf(o4r[M3(2)], d5, g5, &fn);
                    swv.x = __builtin_fmaf(w5, fn.x, swv.x);
                    swv.y = __builtin_fmaf(w5, fn.y, swv.y);
                    gsv.x = __builtin_fmaf(g1, g5.x, gsv.x);
                    gsv.y = __builtin_fmaf(g1, g5.y, gsv.y);
                }
            }
        }
    }
#undef M4
#undef M3
#undef M2
#undef M6

    // apply step-invariant column masks ONCE, wave-reduce, 2 atomics
    float vals[2];
    vals[0] = gsv.x * m0 + gsv.y * m1;
    vals[1] = swv.x * m0 + swv.y * m1;
    const int slot = (strip + chunk * NSTRIP) & (NSLOT - 1);
#pragma unroll
    for (int kk = 0; kk < 2; ++kk) {
        float v = vals[kk];
#pragma unroll
        for (int off = 32; off > 0; off >>= 1)
            v += __shfl_down(v, off, 64);
        if (lane == 0) atomicAdd(&ws[slot * 32 + kk], v);
    }
}

__global__ __launch_bounds__(64) void wlc_final(const float* __restrict__ ws,
                                                float* __restrict__ out)
{
    const int lane = threadIdx.x;
    float t0 = (lane < NSLOT) ? ws[lane * 32 + 0] : 0.f;
    float t1 = (lane < NSLOT) ? ws[lane * 32 + 1] : 0.f;
#pragma unroll
    for (int off = 32; off > 0; off >>= 1) {
        t0 += __shfl_down(t0, off, 64);
        t1 += __shfl_down(t1, off, 64);
    }
    if (lane == 0)
        out[0] = t1 / t0;
}

extern "C" void kernel_launch(void* const* d_in, const int* in_sizes, int n_in,
                              void* d_out, int out_size, void* d_ws, size_t ws_size,
                              hipStream_t stream)
{
    const float* pred = (const float*)d_in[0];
    const float* gtp  = (const float*)d_in[1];
    float* ws = (float*)d_ws;

    hipMemsetAsync(d_ws, 0, NSLOT * 32 * sizeof(float), stream);

    wlc_main<<<dim3(NBLOCK), 64 * WPB, 0, stream>>>(pred, gtp, ws);
    wlc_final<<<1, 64, 0, stream>>>(ws, (float*)d_out);
}